// Round 6
// baseline (675.178 us; speedup 1.0000x reference)
//
#include <hip/hip_runtime.h>
#include <math.h>

#define GG   10000
#define NN0  32
#define EE0  64
#define NFF  64
#define HH   128
#define DD   256
#define BB   4096
#define E2B  8192
#define SIXH 768
#define APAD 36

// ============================================================
// Per-graph fused pipeline, aggregate-first + k-split-y formulation.
// One block (256 threads) per graph; 25.6 KB LDS -> 6 blocks/CU.
// Edges in wave-0 registers; A built with LDS atomics; P3 keeps
// accumulators in registers across the two y-halves (no partial
// round-trip); score/rank/remap fused into one wave-0 phase.
// ============================================================

template<int M, int KK, int K, int SX, bool IND, bool LAST>
__device__ __forceinline__ void stage(
    const float* __restrict__ Wg, const float* __restrict__ bg,
    const float* __restrict__ Wr, const float* __restrict__ Wn, const float* __restrict__ bs,
    float* bufX, float* bufY, float* s_A,
    float* s_dis, float* s_cm, float* s_sc2,
    float* s_v1, float* s_v2, float* s_score, int* s_rank, int* s_inv,
    int& src_r, int& dst_r, float& ew_r,
    float* __restrict__ featg, int t)
{
  constexpr int KH = K / 2;      // y half-width
  constexpr int R3 = M / 4;      // rows per wave in P3

  // P0: raw A[dst][src] += ew via LDS atomics (wave 0, one edge per lane)
  if (t < EE0)
    atomicAdd(&s_A[dst_r*APAD + src_r], ew_r);
  __syncthreads();

  // P1: deg = 1 + row-sum(A) -> dis; cm = dis*g; sc2 = dis^2*g
  if (t < M) {
    float deg = 1.f;
#pragma unroll
    for (int m0 = 0; m0 < M; m0 += 4) {
      const float4 a4 = *(const float4*)(s_A + t*APAD + m0);
      deg += a4.x + a4.y + a4.z + a4.w;
    }
    const float dis = rsqrtf(deg);
    const float gg = IND ? s_score[s_inv[t]] : 1.f;
    s_dis[t] = dis; s_cm[t] = dis*gg; s_sc2[t] = dis*dis*gg;
  }
  __syncthreads();

  float acc[R3][2];
#pragma unroll
  for (int i = 0; i < R3; ++i) { acc[i][0] = 0.f; acc[i][1] = 0.f; }

#pragma unroll
  for (int p = 0; p < 2; ++p) {
    const int kb = p * KH;
    // P2: y[r][kb..kb+KH) = dis_r * sum_m A[r,m]*cm[m]*x[ind(m)] + sc2[r]*x[ind(r)]
    {
      constexpr int CGB = KH / 4;
      constexpr int ACT = M * CGB;
      if (ACT == 256 || t < ACT) {
        const int r  = t / CGB;
        const int c0 = (t % CGB) * 4;
        float4 ac; ac.x = 0.f; ac.y = 0.f; ac.z = 0.f; ac.w = 0.f;
#pragma unroll
        for (int m0 = 0; m0 < M; m0 += 4) {
          const float4 a4  = *(const float4*)(s_A  + r*APAD + m0);
          const float4 cm4 = *(const float4*)(s_cm + m0);
          int4 iv4;
          if (IND) iv4 = *(const int4*)(s_inv + m0);
#pragma unroll
          for (int j = 0; j < 4; ++j) {
            const float aj = (j==0)?a4.x :(j==1)?a4.y :(j==2)?a4.z :a4.w;
            const float cj = (j==0)?cm4.x:(j==1)?cm4.y:(j==2)?cm4.z:cm4.w;
            const int   rm = IND ? ((j==0)?iv4.x:(j==1)?iv4.y:(j==2)?iv4.z:iv4.w) : (m0+j);
            const float cf = aj * cj;
            const float4 xm = *(const float4*)(bufX + rm*SX + kb + c0);
            ac.x = fmaf(cf, xm.x, ac.x);
            ac.y = fmaf(cf, xm.y, ac.y);
            ac.z = fmaf(cf, xm.z, ac.z);
            ac.w = fmaf(cf, xm.w, ac.w);
          }
        }
        const int rr = IND ? s_inv[r] : r;
        const float4 xr = *(const float4*)(bufX + rr*SX + kb + c0);
        const float dr = s_dis[r], sc = s_sc2[r];
        float4 y;
        y.x = fmaf(sc, xr.x, ac.x*dr);
        y.y = fmaf(sc, xr.y, ac.y*dr);
        y.z = fmaf(sc, xr.z, ac.z*dr);
        y.w = fmaf(sc, xr.w, ac.w*dr);
        *(float4*)(bufY + r*KH + c0) = y;
      }
    }
    __syncthreads();
    // P3 partial: acc += y[w-rows][kb..] @ W[kb.., cols]
    {
      const int w  = t >> 6;
      const int cg = t & 63;
#pragma unroll 2
      for (int k0 = 0; k0 < KH; k0 += 4) {
        float4 yv[R3];
#pragma unroll
        for (int i = 0; i < R3; ++i)
          yv[i] = *(const float4*)(bufY + (w*R3 + i)*KH + k0);
#pragma unroll
        for (int j = 0; j < 4; ++j) {
          const float2 w2 = *(const float2*)(Wg + (size_t)(kb + k0 + j)*HH + cg*2);
#pragma unroll
          for (int i = 0; i < R3; ++i) {
            const float yj = (j==0)?yv[i].x:(j==1)?yv[i].y:(j==2)?yv[i].z:yv[i].w;
            acc[i][0] = fmaf(yj, w2.x, acc[i][0]);
            acc[i][1] = fmaf(yj, w2.y, acc[i][1]);
          }
        }
      }
    }
    if (p == 0) __syncthreads();   // protect bufY overwrite by pass 1
  }

  // epilogue: out = relu(acc + b) -> bufX; v1 = out.Wn, v2 = out.Wr (wave reduce)
  {
    const int w  = t >> 6;
    const int cg = t & 63;
    const float2 b2  = *(const float2*)(bg + cg*2);
    const float2 wn2 = *(const float2*)(Wn + cg*2);
    const float2 wr2 = *(const float2*)(Wr + cg*2);
#pragma unroll
    for (int i = 0; i < R3; ++i) {
      const int row = w*R3 + i;
      const float ox = fmaxf(acc[i][0] + b2.x, 0.f);
      const float oy = fmaxf(acc[i][1] + b2.y, 0.f);
      float2 v; v.x = ox; v.y = oy;
      *(float2*)(bufX + row*HH + cg*2) = v;
      float p1 = ox*wn2.x + oy*wn2.y;
      float p2 = ox*wr2.x + oy*wr2.y;
#pragma unroll
      for (int off = 32; off >= 1; off >>= 1) {
        p1 += __shfl_xor(p1, off);
        p2 += __shfl_xor(p2, off);
      }
      if ((t & 63) == 0) { s_v1[row] = p1; s_v2[row] = p2; }
    }
  }
  __syncthreads();

  // P45 (wave 0, wave-synchronous): score -> rank -> inv -> edge remap
  if (t < 64) {
    if (t < M) {
      float sc = bs[0] + s_v2[t];
#pragma unroll
      for (int m0 = 0; m0 < M; m0 += 4) {
        const float4 a4 = *(const float4*)(s_A  + t*APAD + m0);
        const float4 v4 = *(const float4*)(s_v1 + m0);
        sc += a4.x*v4.x + a4.y*v4.y + a4.z*v4.z + a4.w*v4.w;
      }
      s_score[t] = tanhf(sc);
    }
    if (t < M) {
      const float st = s_score[t];
      int r = 0;
      for (int m = 0; m < M; ++m) {
        const float sm = s_score[m];
        r += (sm > st) || (sm == st && m < t);
      }
      s_rank[t] = r;
      if (r < KK) s_inv[r] = t;
    }
    if (!LAST) {
      const int a = s_rank[src_r];
      const int b = s_rank[dst_r];
      const bool val = (a < KK) && (b < KK);
      ew_r  = val ? ew_r : 0.f;
      src_r = val ? a : 0;
      dst_r = val ? b : 0;
    }
  }
  __syncthreads();

  // P6: readout (gmp || gap); prep next stage (zero A)
  {
    const int f = t & 127, which = t >> 7;
    float r_acc = which ? 0.f : -INFINITY;
#pragma unroll
    for (int r = 0; r < KK; ++r) {
      const int n = s_inv[r];
      const float v = bufX[n*HH + f] * s_score[n];
      r_acc = which ? (r_acc + v) : fmaxf(r_acc, v);
    }
    featg[which*HH + f] = which ? r_acc * (1.f/KK) : r_acc;
  }
  if (!LAST) {
    for (int idx = t; idx < NN0*APAD/4; idx += 256) {
      float4 z4; z4.x = 0.f; z4.y = 0.f; z4.z = 0.f; z4.w = 0.f;
      *(float4*)(s_A + idx*4) = z4;
    }
    __syncthreads();
  }
}

__global__ __launch_bounds__(256, 6) void graph_kernel(
    const float* __restrict__ x,
    const int* __restrict__ esrc, const int* __restrict__ edst, const float* __restrict__ ewg,
    const float* __restrict__ W1, const float* __restrict__ b1,
    const float* __restrict__ Ws1r, const float* __restrict__ Ws1n, const float* __restrict__ bs1,
    const float* __restrict__ W2, const float* __restrict__ b2,
    const float* __restrict__ Ws2r, const float* __restrict__ Ws2n, const float* __restrict__ bs2,
    const float* __restrict__ W3, const float* __restrict__ b3,
    const float* __restrict__ Ws3r, const float* __restrict__ Ws3n, const float* __restrict__ bs3,
    float* __restrict__ feat)
{
  __shared__ __align__(16) float bufX[NN0*HH];    // 16 KB: x̂ / out
  __shared__ __align__(16) float bufY[1024];      // 4 KB: y half
  __shared__ __align__(16) float s_A[NN0*APAD];   // 4.5 KB raw adjacency
  __shared__ __align__(16) float s_dis[NN0], s_cm[NN0], s_sc2[NN0];
  __shared__ __align__(16) float s_v1[NN0], s_v2[NN0], s_score[NN0];
  __shared__ __align__(16) int   s_rank[NN0], s_inv[NN0];

  const int t = threadIdx.x;
  const int g = blockIdx.x;

  // load x̂ (packed stride 64)
  for (int idx = t; idx < NN0*NFF/4; idx += 256)
    *(float4*)(bufX + idx*4) = *(const float4*)(x + (size_t)g*NN0*NFF + idx*4);
  // edges -> registers (meaningful in wave 0; every thread holds a copy)
  int src_r, dst_r; float ew_r;
  {
    const int e = g*EE0 + (t & 63);
    src_r = esrc[e] - g*NN0;
    dst_r = edst[e] - g*NN0;
    ew_r  = ewg[e];
  }
  // zero A
  for (int idx = t; idx < NN0*APAD/4; idx += 256) {
    float4 z4; z4.x = 0.f; z4.y = 0.f; z4.z = 0.f; z4.w = 0.f;
    *(float4*)(s_A + idx*4) = z4;
  }
  __syncthreads();

  float* featg = feat + (size_t)g * SIXH;

  stage<NN0, 16, NFF, NFF, false, false>(W1, b1, Ws1r, Ws1n, bs1,
      bufX, bufY, s_A, s_dis, s_cm, s_sc2, s_v1, s_v2, s_score, s_rank, s_inv,
      src_r, dst_r, ew_r, featg, t);
  stage<16, 8, HH, HH, true, false>(W2, b2, Ws2r, Ws2n, bs2,
      bufX, bufY, s_A, s_dis, s_cm, s_sc2, s_v1, s_v2, s_score, s_rank, s_inv,
      src_r, dst_r, ew_r, featg + 256, t);
  stage<8, 4, HH, HH, true, true>(W3, b3, Ws3r, Ws3n, bs3,
      bufX, bufY, s_A, s_dis, s_cm, s_sc2, s_v1, s_v2, s_score, s_rank, s_inv,
      src_r, dst_r, ew_r, featg + 512, t);
}

// ============================================================
// DDI stage
// ============================================================

__global__ void k_deg_init(float* __restrict__ degf) {
  int i = blockIdx.x*256 + threadIdx.x;
  if (i < GG) degf[i] = 1.f;
}

__global__ void k_deg_acc(const int* __restrict__ ddi, float* __restrict__ degf) {
  int e = blockIdx.x*256 + threadIdx.x;
  if (e < E2B) atomicAdd(&degf[ddi[E2B + e]], 1.f);
}

// hdd[G,256] = feat[G,768] @ Wd[768,256]; 12 rows/block -> 834 blocks
__global__ __launch_bounds__(256, 4) void k_ddi_gemm(const float* __restrict__ feat,
    const float* __restrict__ Wd, float* __restrict__ hdd)
{
  __shared__ __align__(16) float s_f[12*SIXH];
  const int t = threadIdx.x;
  const int r0 = blockIdx.x * 12;
  const int cg = t & 63, rg = t >> 6;    // 4 cols x 3 rows per thread
  for (int idx = t; idx < 12*SIXH/4; idx += 256) {
    const int row = idx / 192;           // 192 float4 per row
    float4 v; v.x = 0.f; v.y = 0.f; v.z = 0.f; v.w = 0.f;
    if (r0 + row < GG) v = *(const float4*)(feat + (size_t)r0*SIXH + idx*4);
    *(float4*)(s_f + idx*4) = v;
  }
  __syncthreads();
  float acc[3][4];
#pragma unroll
  for (int i = 0; i < 3; ++i) { acc[i][0]=0.f; acc[i][1]=0.f; acc[i][2]=0.f; acc[i][3]=0.f; }
#pragma unroll 4
  for (int k = 0; k < SIXH; ++k) {
    const float4 w = *(const float4*)(Wd + (size_t)k*DD + cg*4);
#pragma unroll
    for (int i = 0; i < 3; ++i) {
      const float a = s_f[(rg*3 + i)*SIXH + k];   // broadcast
      acc[i][0]=fmaf(a,w.x,acc[i][0]); acc[i][1]=fmaf(a,w.y,acc[i][1]);
      acc[i][2]=fmaf(a,w.z,acc[i][2]); acc[i][3]=fmaf(a,w.w,acc[i][3]);
    }
  }
#pragma unroll
  for (int i = 0; i < 3; ++i) {
    const int row = r0 + rg*3 + i;
    if (row < GG) {
      float4 v; v.x=acc[i][0]; v.y=acc[i][1]; v.z=acc[i][2]; v.w=acc[i][3];
      *(float4*)(hdd + (size_t)row*DD + cg*4) = v;
    }
  }
}

__global__ void k_z_init(const float* __restrict__ hdd, const float* __restrict__ degf,
                         const float* __restrict__ bd, float* __restrict__ z)
{
  int idx = blockIdx.x*256 + threadIdx.x;
  if (idx < GG*DD) {
    int g = idx >> 8, f = idx & 255;
    z[idx] = hdd[idx] / degf[g] + bd[f];
  }
}

// 4 edges per block
__global__ void k_scatter(const int* __restrict__ ddi, const float* __restrict__ degf,
                          const float* __restrict__ hdd, float* __restrict__ z)
{
  const int t = threadIdx.x;
#pragma unroll
  for (int j = 0; j < 4; ++j) {
    const int e = blockIdx.x*4 + j;
    const int s = ddi[e], d = ddi[E2B + e];
    const float nrm = rsqrtf(degf[s]) * rsqrtf(degf[d]);
    atomicAdd(&z[(size_t)d*DD + t], nrm * hdd[(size_t)s*DD + t]);
  }
}

// link-prediction heads + row norms; 8 edges per block -> 1024 blocks
__global__ __launch_bounds__(256) void k_final(const float* __restrict__ z,
    const int* __restrict__ ddi, const float* __restrict__ attr,
    const float* __restrict__ Wl1, const float* __restrict__ bl1,
    const float* __restrict__ Wl2, const float* __restrict__ bl2,
    const float* __restrict__ Wl3, const float* __restrict__ bl3,
    float* __restrict__ out)
{
  __shared__ __align__(16) float s_u[8*257];
  const int t = threadIdx.x;
  const int e0 = blockIdx.x * 8;
  float lacc[8], acc[8];

  // ---- X = sigmoid(relu(z[src]) @ Wl1 + bl1)
  for (int idx = t; idx < 8*256; idx += 256) {
    const int r = idx >> 8, k = idx & 255;
    const int src = ddi[e0 + r];
    s_u[r*257 + k] = fmaxf(z[(size_t)src*DD + k], 0.f);
  }
  __syncthreads();
#pragma unroll
  for (int r = 0; r < 8; ++r) acc[r] = bl1[t];
#pragma unroll 4
  for (int k = 0; k < 256; ++k) {
    const float w = Wl1[(size_t)k*DD + t];
#pragma unroll
    for (int r = 0; r < 8; ++r) acc[r] = fmaf(s_u[r*257 + k], w, acc[r]);
  }
#pragma unroll
  for (int r = 0; r < 8; ++r) {
    const float sx = 1.f / (1.f + expf(-acc[r]));
    lacc[r] = sx;
    const int e = e0 + r;
    if (e < BB) out[12288 + (size_t)e*DD + t] = sx;
  }
  __syncthreads();

  // ---- Y = sigmoid(relu(z[dst]) @ Wl2 + bl2)
  for (int idx = t; idx < 8*256; idx += 256) {
    const int r = idx >> 8, k = idx & 255;
    const int dst = ddi[E2B + e0 + r];
    s_u[r*257 + k] = fmaxf(z[(size_t)dst*DD + k], 0.f);
  }
  __syncthreads();
#pragma unroll
  for (int r = 0; r < 8; ++r) acc[r] = bl2[t];
#pragma unroll 4
  for (int k = 0; k < 256; ++k) {
    const float w = Wl2[(size_t)k*DD + t];
#pragma unroll
    for (int r = 0; r < 8; ++r) acc[r] = fmaf(s_u[r*257 + k], w, acc[r]);
  }
#pragma unroll
  for (int r = 0; r < 8; ++r) lacc[r] -= 1.f / (1.f + expf(-acc[r]));
  __syncthreads();

  // ---- A = sigmoid(attr @ Wl3 + bl3)
  for (int idx = t; idx < 8*64; idx += 256) {
    const int r = idx >> 6, k = idx & 63;
    s_u[r*257 + k] = attr[(size_t)(e0 + r)*NFF + k];
  }
  __syncthreads();
#pragma unroll
  for (int r = 0; r < 8; ++r) acc[r] = bl3[t];
#pragma unroll 4
  for (int k = 0; k < 64; ++k) {
    const float w = Wl3[(size_t)k*DD + t];
#pragma unroll
    for (int r = 0; r < 8; ++r) acc[r] = fmaf(s_u[r*257 + k], w, acc[r]);
  }
#pragma unroll
  for (int r = 0; r < 8; ++r) lacc[r] += 1.f / (1.f + expf(-acc[r]));
  __syncthreads();

  // ---- squared residual, 32-lane row reduce
#pragma unroll
  for (int r = 0; r < 8; ++r) s_u[r*257 + t] = lacc[r]*lacc[r];
  __syncthreads();
  {
    const int row = t >> 5, l = t & 31;
    float s = 0.f;
#pragma unroll
    for (int j = 0; j < 8; ++j) s += s_u[row*257 + l + 32*j];
#pragma unroll
    for (int off = 16; off >= 1; off >>= 1) s += __shfl_xor(s, off);
    if (l == 0) {
      const float nrm = sqrtf(s);
      const int e = e0 + row;
      if (e < BB) out[4096 + e] = nrm;
      else        out[8192 + (e - BB)] = nrm;
    }
  }
}

__global__ void k_loss(float* __restrict__ out) {
  int i = blockIdx.x*256 + threadIdx.x;
  if (i < BB) out[i] = 2.f*(float)DD - out[4096 + i] + 0.5f*out[8192 + i];
}

// ============================================================

extern "C" void kernel_launch(void* const* d_in, const int* in_sizes, int n_in,
                              void* d_out, int out_size, void* d_ws, size_t ws_size,
                              hipStream_t stream)
{
  const float* x    = (const float*)d_in[0];
  const int*   esrc = (const int*)d_in[1];
  const int*   edst = (const int*)d_in[2];
  const float* ewt  = (const float*)d_in[3];
  const int*   ddi  = (const int*)d_in[4];
  const float* attr = (const float*)d_in[5];
  const float* W1   = (const float*)d_in[6];  const float* b1  = (const float*)d_in[7];
  const float* Ws1r = (const float*)d_in[8];  const float* Ws1n= (const float*)d_in[9];  const float* bs1 = (const float*)d_in[10];
  const float* W2   = (const float*)d_in[11]; const float* b2  = (const float*)d_in[12];
  const float* Ws2r = (const float*)d_in[13]; const float* Ws2n= (const float*)d_in[14]; const float* bs2 = (const float*)d_in[15];
  const float* W3   = (const float*)d_in[16]; const float* b3  = (const float*)d_in[17];
  const float* Ws3r = (const float*)d_in[18]; const float* Ws3n= (const float*)d_in[19]; const float* bs3 = (const float*)d_in[20];
  const float* Wd   = (const float*)d_in[21]; const float* bd  = (const float*)d_in[22];
  const float* Wl1  = (const float*)d_in[23]; const float* bl1 = (const float*)d_in[24];
  const float* Wl2  = (const float*)d_in[25]; const float* bl2 = (const float*)d_in[26];
  const float* Wl3  = (const float*)d_in[27]; const float* bl3 = (const float*)d_in[28];

  float* ws   = (float*)d_ws;
  float* feat = ws;
  float* hdd  = feat + (size_t)GG*SIXH;
  float* zb   = hdd  + (size_t)GG*DD;
  float* degf = zb   + (size_t)GG*DD;
  float* out  = (float*)d_out;

  graph_kernel<<<GG, 256, 0, stream>>>(x, esrc, edst, ewt,
      W1, b1, Ws1r, Ws1n, bs1, W2, b2, Ws2r, Ws2n, bs2, W3, b3, Ws3r, Ws3n, bs3, feat);
  k_deg_init<<<(GG + 255)/256, 256, 0, stream>>>(degf);
  k_deg_acc<<<(E2B + 255)/256, 256, 0, stream>>>(ddi, degf);
  k_ddi_gemm<<<(GG + 11)/12, 256, 0, stream>>>(feat, Wd, hdd);
  k_z_init<<<(GG*DD + 255)/256, 256, 0, stream>>>(hdd, degf, bd, zb);
  k_scatter<<<E2B/4, 256, 0, stream>>>(ddi, degf, hdd, zb);
  k_final<<<E2B/8, 256, 0, stream>>>(zb, ddi, attr, Wl1, bl1, Wl2, bl2, Wl3, bl3, out);
  k_loss<<<(BB + 255)/256, 256, 0, stream>>>(out);
}

// Round 7
// 512.303 us; speedup vs baseline: 1.3179x; 1.3179x over previous
//
#include <hip/hip_runtime.h>
#include <math.h>

#define GG   10000
#define NN0  32
#define EE0  64
#define NFF  64
#define HH   128
#define DD   256
#define BB   4096
#define E2B  8192
#define SIXH 768
#define APAD 36

// ============================================================
// Per-graph fused pipeline, aggregate-first formulation (round-4
// memory structure: full-K bufY, wave-pair k-split P3).
// Round-6 pieces kept: LDS-atomic A-build, fused wave-0
// score/rank/remap phase, edges in wave-0 registers.
// ~29.6 KB LDS -> 5 blocks/CU.
// ============================================================

template<int M, int KK, int K, int SX, bool IND, bool LAST>
__device__ __forceinline__ void stage(
    const float* __restrict__ Wg, const float* __restrict__ bg,
    const float* __restrict__ Wr, const float* __restrict__ Wn, const float* __restrict__ bs,
    float* bufX, float* bufY, float* s_A,
    float* s_dis, float* s_cm, float* s_sc2,
    float* s_v1, float* s_v2, float* s_score, int* s_rank, int* s_inv,
    int& src_r, int& dst_r, float& ew_r,
    float* __restrict__ featg, int t)
{
  // P0: raw A[dst][src] += ew via LDS atomics (wave 0, one edge per lane)
  if (t < EE0)
    atomicAdd(&s_A[dst_r*APAD + src_r], ew_r);
  __syncthreads();

  // P1: deg = 1 + row-sum(A) -> dis; cm = dis*g; sc2 = dis^2*g
  if (t < M) {
    float deg = 1.f;
#pragma unroll
    for (int m0 = 0; m0 < M; m0 += 4) {
      const float4 a4 = *(const float4*)(s_A + t*APAD + m0);
      deg += a4.x + a4.y + a4.z + a4.w;
    }
    const float dis = rsqrtf(deg);
    const float gg = IND ? s_score[s_inv[t]] : 1.f;
    s_dis[t] = dis; s_cm[t] = dis*gg; s_sc2[t] = dis*dis*gg;
  }
  __syncthreads();

  // P2: y[r] = dis_r * sum_m A[r,m]*cm[m]*x[ind(m)] + sc2[r]*x[ind(r)]  (full K)
  {
    constexpr int CGB = K/4, RGB = 256/CGB, R = M/RGB;
    const int cg = t % CGB, rg = t / CGB;
    const int c0 = cg * 4;
    float acc[R][4];
#pragma unroll
    for (int i = 0; i < R; ++i) { acc[i][0]=0.f; acc[i][1]=0.f; acc[i][2]=0.f; acc[i][3]=0.f; }
#pragma unroll 2
    for (int m0 = 0; m0 < M; m0 += 4) {
      float4 a[R];
#pragma unroll
      for (int i = 0; i < R; ++i)
        a[i] = *(const float4*)(s_A + (rg*R + i)*APAD + m0);
#pragma unroll
      for (int j = 0; j < 4; ++j) {
        const int m = m0 + j;
        const int row = IND ? s_inv[m] : m;
        const float4 xv = *(const float4*)(bufX + row*SX + c0);
        const float cmm = s_cm[m];
#pragma unroll
        for (int i = 0; i < R; ++i) {
          const float aj = (j==0) ? a[i].x : (j==1) ? a[i].y : (j==2) ? a[i].z : a[i].w;
          const float cf = aj * cmm;
          acc[i][0] = fmaf(cf, xv.x, acc[i][0]);
          acc[i][1] = fmaf(cf, xv.y, acc[i][1]);
          acc[i][2] = fmaf(cf, xv.z, acc[i][2]);
          acc[i][3] = fmaf(cf, xv.w, acc[i][3]);
        }
      }
    }
#pragma unroll
    for (int i = 0; i < R; ++i) {
      const int r = rg*R + i;
      const int rr = IND ? s_inv[r] : r;
      const float4 xv = *(const float4*)(bufX + rr*SX + c0);
      const float dr = s_dis[r], sc = s_sc2[r];
      float4 v;
      v.x = fmaf(sc, xv.x, acc[i][0]*dr);
      v.y = fmaf(sc, xv.y, acc[i][1]*dr);
      v.z = fmaf(sc, xv.z, acc[i][2]*dr);
      v.w = fmaf(sc, xv.w, acc[i][3]*dr);
      *(float4*)(bufY + r*K + c0) = v;
    }
  }
  __syncthreads();

  // P3: out = relu(y @ W + b) -> bufX; fused v1 = out.Wn, v2 = out.Wr
  if constexpr (K != HH) {
    // ---- stage 1 (K=64): duplicate-free f2 layout, no k-split
    constexpr int R = M / 4;
    const int cg = t & 63;
    const int rg = t >> 6;
    float acc0[R], acc1[R];
#pragma unroll
    for (int i = 0; i < R; ++i) { acc0[i]=0.f; acc1[i]=0.f; }
#pragma unroll 2
    for (int k0 = 0; k0 < K; k0 += 4) {
      float4 yv[R];
#pragma unroll
      for (int i = 0; i < R; ++i)     // broadcast (wave-uniform addr)
        yv[i] = *(const float4*)(bufY + (rg*R + i)*K + k0);
#pragma unroll
      for (int j = 0; j < 4; ++j) {
        const float2 w = *(const float2*)(Wg + (size_t)(k0+j)*HH + cg*2);
#pragma unroll
        for (int i = 0; i < R; ++i) {
          const float yj = (j==0) ? yv[i].x : (j==1) ? yv[i].y : (j==2) ? yv[i].z : yv[i].w;
          acc0[i] = fmaf(yj, w.x, acc0[i]);
          acc1[i] = fmaf(yj, w.y, acc1[i]);
        }
      }
    }
    const float2 b2  = *(const float2*)(bg + cg*2);
    const float2 wn2 = *(const float2*)(Wn + cg*2);
    const float2 wr2 = *(const float2*)(Wr + cg*2);
#pragma unroll
    for (int i = 0; i < R; ++i) {
      const int row = rg*R + i;
      const float ox = fmaxf(acc0[i] + b2.x, 0.f);
      const float oy = fmaxf(acc1[i] + b2.y, 0.f);
      float2 v; v.x=ox; v.y=oy;
      *(float2*)(bufX + row*HH + cg*2) = v;
      float p1 = ox*wn2.x + oy*wn2.y;
      float p2 = ox*wr2.x + oy*wr2.y;
#pragma unroll
      for (int off = 32; off >= 1; off >>= 1) {
        p1 += __shfl_xor(p1, off);
        p2 += __shfl_xor(p2, off);
      }
      if ((t & 63) == 0) { s_v1[row] = p1; s_v2[row] = p2; }
    }
  } else {
    // ---- stages 2/3 (K=128): k-split across wave-pairs + partial reduce
    constexpr int R = M / 2;
    const int cg  = t & 63;
    const int sub = (t >> 6) & 1;
    const int pr  = t >> 7;
    const int kbase = pr * (K/2);
    float acc0[R], acc1[R];
#pragma unroll
    for (int i = 0; i < R; ++i) { acc0[i]=0.f; acc1[i]=0.f; }
#pragma unroll 2
    for (int k0 = 0; k0 < K/2; k0 += 4) {
      float4 yv[R];
#pragma unroll
      for (int i = 0; i < R; ++i)     // broadcast (wave-uniform addr)
        yv[i] = *(const float4*)(bufY + (sub*R + i)*K + kbase + k0);
#pragma unroll
      for (int j = 0; j < 4; ++j) {
        const float2 w = *(const float2*)(Wg + (size_t)(kbase+k0+j)*HH + cg*2);
#pragma unroll
        for (int i = 0; i < R; ++i) {
          const float yj = (j==0) ? yv[i].x : (j==1) ? yv[i].y : (j==2) ? yv[i].z : yv[i].w;
          acc0[i] = fmaf(yj, w.x, acc0[i]);
          acc1[i] = fmaf(yj, w.y, acc1[i]);
        }
      }
    }
    __syncthreads();                  // all y reads done
    float* pdst = pr ? bufY : bufX;   // wave-uniform select
#pragma unroll
    for (int i = 0; i < R; ++i) {
      float2 v; v.x=acc0[i]; v.y=acc1[i];
      *(float2*)(pdst + (sub*R + i)*HH + cg*2) = v;
    }
    __syncthreads();
    // epilogue: sum partials + bias + relu + v1/v2
    constexpr int RE = M / 8;
    const int ecg = t & 31, erg = t >> 5;
    const int f0 = ecg * 4;
    const float4 b4  = *(const float4*)(bg + f0);
    const float4 wn4 = *(const float4*)(Wn + f0);
    const float4 wr4 = *(const float4*)(Wr + f0);
#pragma unroll
    for (int i = 0; i < RE; ++i) {
      const int row = erg*RE + i;
      const float4 p0 = *(const float4*)(bufX + row*HH + f0);
      const float4 p1v = *(const float4*)(bufY + row*HH + f0);
      const float ox = fmaxf(p0.x + p1v.x + b4.x, 0.f);
      const float oy = fmaxf(p0.y + p1v.y + b4.y, 0.f);
      const float oz = fmaxf(p0.z + p1v.z + b4.z, 0.f);
      const float ow = fmaxf(p0.w + p1v.w + b4.w, 0.f);
      float4 v; v.x=ox; v.y=oy; v.z=oz; v.w=ow;
      *(float4*)(bufX + row*HH + f0) = v;
      float p1 = ox*wn4.x + oy*wn4.y + oz*wn4.z + ow*wn4.w;
      float p2 = ox*wr4.x + oy*wr4.y + oz*wr4.z + ow*wr4.w;
#pragma unroll
      for (int off = 16; off >= 1; off >>= 1) {
        p1 += __shfl_xor(p1, off);
        p2 += __shfl_xor(p2, off);
      }
      if ((t & 31) == 0) { s_v1[row] = p1; s_v2[row] = p2; }
    }
  }
  __syncthreads();

  // P45 (wave 0, wave-synchronous): score -> rank -> inv -> edge remap
  if (t < 64) {
    if (t < M) {
      float sc = bs[0] + s_v2[t];
#pragma unroll
      for (int m0 = 0; m0 < M; m0 += 4) {
        const float4 a4 = *(const float4*)(s_A  + t*APAD + m0);
        const float4 v4 = *(const float4*)(s_v1 + m0);
        sc += a4.x*v4.x + a4.y*v4.y + a4.z*v4.z + a4.w*v4.w;
      }
      s_score[t] = tanhf(sc);
    }
    if (t < M) {
      const float st = s_score[t];
      int r = 0;
      for (int m = 0; m < M; ++m) {
        const float sm = s_score[m];
        r += (sm > st) || (sm == st && m < t);
      }
      s_rank[t] = r;
      if (r < KK) s_inv[r] = t;
    }
    if (!LAST) {
      const int a = s_rank[src_r];
      const int b = s_rank[dst_r];
      const bool val = (a < KK) && (b < KK);
      ew_r  = val ? ew_r : 0.f;
      src_r = val ? a : 0;
      dst_r = val ? b : 0;
    }
  }
  __syncthreads();

  // P6: readout (gmp || gap); zero A for next stage
  {
    const int f = t & 127, which = t >> 7;
    float r_acc = which ? 0.f : -INFINITY;
#pragma unroll
    for (int r = 0; r < KK; ++r) {
      const int n = s_inv[r];
      const float v = bufX[n*HH + f] * s_score[n];
      r_acc = which ? (r_acc + v) : fmaxf(r_acc, v);
    }
    featg[which*HH + f] = which ? r_acc * (1.f/KK) : r_acc;
  }
  if (!LAST) {
    for (int idx = t; idx < NN0*APAD/4; idx += 256) {
      float4 z4; z4.x = 0.f; z4.y = 0.f; z4.z = 0.f; z4.w = 0.f;
      *(float4*)(s_A + idx*4) = z4;
    }
  }
  __syncthreads();
}

__global__ __launch_bounds__(256, 5) void graph_kernel(
    const float* __restrict__ x,
    const int* __restrict__ esrc, const int* __restrict__ edst, const float* __restrict__ ewg,
    const float* __restrict__ W1, const float* __restrict__ b1,
    const float* __restrict__ Ws1r, const float* __restrict__ Ws1n, const float* __restrict__ bs1,
    const float* __restrict__ W2, const float* __restrict__ b2,
    const float* __restrict__ Ws2r, const float* __restrict__ Ws2n, const float* __restrict__ bs2,
    const float* __restrict__ W3, const float* __restrict__ b3,
    const float* __restrict__ Ws3r, const float* __restrict__ Ws3n, const float* __restrict__ bs3,
    float* __restrict__ feat)
{
  __shared__ __align__(16) float bufX[NN0*HH];    // 16 KB: x̂ / out / partial-lo
  __shared__ __align__(16) float bufY[2048];      // 8 KB: y (stride K) / partial-hi
  __shared__ __align__(16) float s_A[NN0*APAD];   // 4.5 KB raw adjacency
  __shared__ __align__(16) float s_dis[NN0], s_cm[NN0], s_sc2[NN0];
  __shared__ __align__(16) float s_v1[NN0], s_v2[NN0], s_score[NN0];
  __shared__ __align__(16) int   s_rank[NN0], s_inv[NN0];

  const int t = threadIdx.x;
  const int g = blockIdx.x;

  // load x̂ (packed stride 64)
  for (int idx = t; idx < NN0*NFF/4; idx += 256)
    *(float4*)(bufX + idx*4) = *(const float4*)(x + (size_t)g*NN0*NFF + idx*4);
  // edges -> registers (used by wave 0)
  int src_r, dst_r; float ew_r;
  {
    const int e = g*EE0 + (t & 63);
    src_r = esrc[e] - g*NN0;
    dst_r = edst[e] - g*NN0;
    ew_r  = ewg[e];
  }
  // zero A
  for (int idx = t; idx < NN0*APAD/4; idx += 256) {
    float4 z4; z4.x = 0.f; z4.y = 0.f; z4.z = 0.f; z4.w = 0.f;
    *(float4*)(s_A + idx*4) = z4;
  }
  __syncthreads();

  float* featg = feat + (size_t)g * SIXH;

  stage<NN0, 16, NFF, NFF, false, false>(W1, b1, Ws1r, Ws1n, bs1,
      bufX, bufY, s_A, s_dis, s_cm, s_sc2, s_v1, s_v2, s_score, s_rank, s_inv,
      src_r, dst_r, ew_r, featg, t);
  stage<16, 8, HH, HH, true, false>(W2, b2, Ws2r, Ws2n, bs2,
      bufX, bufY, s_A, s_dis, s_cm, s_sc2, s_v1, s_v2, s_score, s_rank, s_inv,
      src_r, dst_r, ew_r, featg + 256, t);
  stage<8, 4, HH, HH, true, true>(W3, b3, Ws3r, Ws3n, bs3,
      bufX, bufY, s_A, s_dis, s_cm, s_sc2, s_v1, s_v2, s_score, s_rank, s_inv,
      src_r, dst_r, ew_r, featg + 512, t);
}

// ============================================================
// DDI stage
// ============================================================

__global__ void k_deg_init(float* __restrict__ degf) {
  int i = blockIdx.x*256 + threadIdx.x;
  if (i < GG) degf[i] = 1.f;
}

__global__ void k_deg_acc(const int* __restrict__ ddi, float* __restrict__ degf) {
  int e = blockIdx.x*256 + threadIdx.x;
  if (e < E2B) atomicAdd(&degf[ddi[E2B + e]], 1.f);
}

// hdd[G,256] = feat[G,768] @ Wd[768,256]; 12 rows/block -> 834 blocks
__global__ __launch_bounds__(256, 4) void k_ddi_gemm(const float* __restrict__ feat,
    const float* __restrict__ Wd, float* __restrict__ hdd)
{
  __shared__ __align__(16) float s_f[12*SIXH];
  const int t = threadIdx.x;
  const int r0 = blockIdx.x * 12;
  const int cg = t & 63, rg = t >> 6;    // 4 cols x 3 rows per thread
  for (int idx = t; idx < 12*SIXH/4; idx += 256) {
    const int row = idx / 192;           // 192 float4 per row
    float4 v; v.x = 0.f; v.y = 0.f; v.z = 0.f; v.w = 0.f;
    if (r0 + row < GG) v = *(const float4*)(feat + (size_t)r0*SIXH + idx*4);
    *(float4*)(s_f + idx*4) = v;
  }
  __syncthreads();
  float acc[3][4];
#pragma unroll
  for (int i = 0; i < 3; ++i) { acc[i][0]=0.f; acc[i][1]=0.f; acc[i][2]=0.f; acc[i][3]=0.f; }
#pragma unroll 4
  for (int k = 0; k < SIXH; ++k) {
    const float4 w = *(const float4*)(Wd + (size_t)k*DD + cg*4);
#pragma unroll
    for (int i = 0; i < 3; ++i) {
      const float a = s_f[(rg*3 + i)*SIXH + k];   // broadcast
      acc[i][0]=fmaf(a,w.x,acc[i][0]); acc[i][1]=fmaf(a,w.y,acc[i][1]);
      acc[i][2]=fmaf(a,w.z,acc[i][2]); acc[i][3]=fmaf(a,w.w,acc[i][3]);
    }
  }
#pragma unroll
  for (int i = 0; i < 3; ++i) {
    const int row = r0 + rg*3 + i;
    if (row < GG) {
      float4 v; v.x=acc[i][0]; v.y=acc[i][1]; v.z=acc[i][2]; v.w=acc[i][3];
      *(float4*)(hdd + (size_t)row*DD + cg*4) = v;
    }
  }
}

__global__ void k_z_init(const float* __restrict__ hdd, const float* __restrict__ degf,
                         const float* __restrict__ bd, float* __restrict__ z)
{
  int idx = blockIdx.x*256 + threadIdx.x;
  if (idx < GG*DD) {
    int g = idx >> 8, f = idx & 255;
    z[idx] = hdd[idx] / degf[g] + bd[f];
  }
}

// 4 edges per block
__global__ void k_scatter(const int* __restrict__ ddi, const float* __restrict__ degf,
                          const float* __restrict__ hdd, float* __restrict__ z)
{
  const int t = threadIdx.x;
#pragma unroll
  for (int j = 0; j < 4; ++j) {
    const int e = blockIdx.x*4 + j;
    const int s = ddi[e], d = ddi[E2B + e];
    const float nrm = rsqrtf(degf[s]) * rsqrtf(degf[d]);
    atomicAdd(&z[(size_t)d*DD + t], nrm * hdd[(size_t)s*DD + t]);
  }
}

// link-prediction heads + row norms; 8 edges per block -> 1024 blocks
__global__ __launch_bounds__(256) void k_final(const float* __restrict__ z,
    const int* __restrict__ ddi, const float* __restrict__ attr,
    const float* __restrict__ Wl1, const float* __restrict__ bl1,
    const float* __restrict__ Wl2, const float* __restrict__ bl2,
    const float* __restrict__ Wl3, const float* __restrict__ bl3,
    float* __restrict__ out)
{
  __shared__ __align__(16) float s_u[8*257];
  const int t = threadIdx.x;
  const int e0 = blockIdx.x * 8;
  float lacc[8], acc[8];

  // ---- X = sigmoid(relu(z[src]) @ Wl1 + bl1)
  for (int idx = t; idx < 8*256; idx += 256) {
    const int r = idx >> 8, k = idx & 255;
    const int src = ddi[e0 + r];
    s_u[r*257 + k] = fmaxf(z[(size_t)src*DD + k], 0.f);
  }
  __syncthreads();
#pragma unroll
  for (int r = 0; r < 8; ++r) acc[r] = bl1[t];
#pragma unroll 4
  for (int k = 0; k < 256; ++k) {
    const float w = Wl1[(size_t)k*DD + t];
#pragma unroll
    for (int r = 0; r < 8; ++r) acc[r] = fmaf(s_u[r*257 + k], w, acc[r]);
  }
#pragma unroll
  for (int r = 0; r < 8; ++r) {
    const float sx = 1.f / (1.f + expf(-acc[r]));
    lacc[r] = sx;
    const int e = e0 + r;
    if (e < BB) out[12288 + (size_t)e*DD + t] = sx;
  }
  __syncthreads();

  // ---- Y = sigmoid(relu(z[dst]) @ Wl2 + bl2)
  for (int idx = t; idx < 8*256; idx += 256) {
    const int r = idx >> 8, k = idx & 255;
    const int dst = ddi[E2B + e0 + r];
    s_u[r*257 + k] = fmaxf(z[(size_t)dst*DD + k], 0.f);
  }
  __syncthreads();
#pragma unroll
  for (int r = 0; r < 8; ++r) acc[r] = bl2[t];
#pragma unroll 4
  for (int k = 0; k < 256; ++k) {
    const float w = Wl2[(size_t)k*DD + t];
#pragma unroll
    for (int r = 0; r < 8; ++r) acc[r] = fmaf(s_u[r*257 + k], w, acc[r]);
  }
#pragma unroll
  for (int r = 0; r < 8; ++r) lacc[r] -= 1.f / (1.f + expf(-acc[r]));
  __syncthreads();

  // ---- A = sigmoid(attr @ Wl3 + bl3)
  for (int idx = t; idx < 8*64; idx += 256) {
    const int r = idx >> 6, k = idx & 63;
    s_u[r*257 + k] = attr[(size_t)(e0 + r)*NFF + k];
  }
  __syncthreads();
#pragma unroll
  for (int r = 0; r < 8; ++r) acc[r] = bl3[t];
#pragma unroll 4
  for (int k = 0; k < 64; ++k) {
    const float w = Wl3[(size_t)k*DD + t];
#pragma unroll
    for (int r = 0; r < 8; ++r) acc[r] = fmaf(s_u[r*257 + k], w, acc[r]);
  }
#pragma unroll
  for (int r = 0; r < 8; ++r) lacc[r] += 1.f / (1.f + expf(-acc[r]));
  __syncthreads();

  // ---- squared residual, 32-lane row reduce
#pragma unroll
  for (int r = 0; r < 8; ++r) s_u[r*257 + t] = lacc[r]*lacc[r];
  __syncthreads();
  {
    const int row = t >> 5, l = t & 31;
    float s = 0.f;
#pragma unroll
    for (int j = 0; j < 8; ++j) s += s_u[row*257 + l + 32*j];
#pragma unroll
    for (int off = 16; off >= 1; off >>= 1) s += __shfl_xor(s, off);
    if (l == 0) {
      const float nrm = sqrtf(s);
      const int e = e0 + row;
      if (e < BB) out[4096 + e] = nrm;
      else        out[8192 + (e - BB)] = nrm;
    }
  }
}

__global__ void k_loss(float* __restrict__ out) {
  int i = blockIdx.x*256 + threadIdx.x;
  if (i < BB) out[i] = 2.f*(float)DD - out[4096 + i] + 0.5f*out[8192 + i];
}

// ============================================================

extern "C" void kernel_launch(void* const* d_in, const int* in_sizes, int n_in,
                              void* d_out, int out_size, void* d_ws, size_t ws_size,
                              hipStream_t stream)
{
  const float* x    = (const float*)d_in[0];
  const int*   esrc = (const int*)d_in[1];
  const int*   edst = (const int*)d_in[2];
  const float* ewt  = (const float*)d_in[3];
  const int*   ddi  = (const int*)d_in[4];
  const float* attr = (const float*)d_in[5];
  const float* W1   = (const float*)d_in[6];  const float* b1  = (const float*)d_in[7];
  const float* Ws1r = (const float*)d_in[8];  const float* Ws1n= (const float*)d_in[9];  const float* bs1 = (const float*)d_in[10];
  const float* W2   = (const float*)d_in[11]; const float* b2  = (const float*)d_in[12];
  const float* Ws2r = (const float*)d_in[13]; const float* Ws2n= (const float*)d_in[14]; const float* bs2 = (const float*)d_in[15];
  const float* W3   = (const float*)d_in[16]; const float* b3  = (const float*)d_in[17];
  const float* Ws3r = (const float*)d_in[18]; const float* Ws3n= (const float*)d_in[19]; const float* bs3 = (const float*)d_in[20];
  const float* Wd   = (const float*)d_in[21]; const float* bd  = (const float*)d_in[22];
  const float* Wl1  = (const float*)d_in[23]; const float* bl1 = (const float*)d_in[24];
  const float* Wl2  = (const float*)d_in[25]; const float* bl2 = (const float*)d_in[26];
  const float* Wl3  = (const float*)d_in[27]; const float* bl3 = (const float*)d_in[28];

  float* ws   = (float*)d_ws;
  float* feat = ws;
  float* hdd  = feat + (size_t)GG*SIXH;
  float* zb   = hdd  + (size_t)GG*DD;
  float* degf = zb   + (size_t)GG*DD;
  float* out  = (float*)d_out;

  graph_kernel<<<GG, 256, 0, stream>>>(x, esrc, edst, ewt,
      W1, b1, Ws1r, Ws1n, bs1, W2, b2, Ws2r, Ws2n, bs2, W3, b3, Ws3r, Ws3n, bs3, feat);
  k_deg_init<<<(GG + 255)/256, 256, 0, stream>>>(degf);
  k_deg_acc<<<(E2B + 255)/256, 256, 0, stream>>>(ddi, degf);
  k_ddi_gemm<<<(GG + 11)/12, 256, 0, stream>>>(feat, Wd, hdd);
  k_z_init<<<(GG*DD + 255)/256, 256, 0, stream>>>(hdd, degf, bd, zb);
  k_scatter<<<E2B/4, 256, 0, stream>>>(ddi, degf, hdd, zb);
  k_final<<<E2B/8, 256, 0, stream>>>(zb, ddi, attr, Wl1, bl1, Wl2, bl2, Wl3, bl3, out);
  k_loss<<<(BB + 255)/256, 256, 0, stream>>>(out);
}